// Round 1
// baseline (561.649 us; speedup 1.0000x reference)
//
#include <hip/hip_runtime.h>
#include <hip/hip_bf16.h>
#include <stdint.h>

#define N_TOK 16384
#define D_IN  2048
#define D_HID 2048

typedef __attribute__((ext_vector_type(8))) short  bf16x8;
typedef __attribute__((ext_vector_type(4))) float  f32x4;
typedef __attribute__((ext_vector_type(8))) unsigned short u16x8;

__device__ __forceinline__ unsigned short f2bf(float f) {
    unsigned int u = __float_as_uint(f);
    u = (u + 0x7FFFu + ((u >> 16) & 1u)) >> 16;
    return (unsigned short)u;
}

// ---------------------------------------------------------------- gate ----
// One wave per token: logits = x[n,:] @ W_gate + b_gate; softmax; top-2
// values (descending) -> s12. Token 0 additionally writes its top-2 indices.
__global__ void gate_kernel(const float* __restrict__ x,
                            const float* __restrict__ Wg,
                            const float* __restrict__ bg,
                            float* __restrict__ s12,
                            int* __restrict__ eidx) {
    const int token = blockIdx.x * 4 + (threadIdx.x >> 6);
    const int lane  = threadIdx.x & 63;
    const float* xr = x + (size_t)token * D_IN;

    float acc[8];
#pragma unroll
    for (int e = 0; e < 8; ++e) acc[e] = 0.f;

    for (int i = lane; i < D_IN; i += 64) {
        float xv = xr[i];
        const float4* wr = (const float4*)(Wg + (size_t)i * 8);
        float4 w0 = wr[0], w1 = wr[1];
        acc[0] += xv * w0.x; acc[1] += xv * w0.y;
        acc[2] += xv * w0.z; acc[3] += xv * w0.w;
        acc[4] += xv * w1.x; acc[5] += xv * w1.y;
        acc[6] += xv * w1.z; acc[7] += xv * w1.w;
    }
#pragma unroll
    for (int off = 32; off > 0; off >>= 1) {
#pragma unroll
        for (int e = 0; e < 8; ++e) acc[e] += __shfl_xor(acc[e], off);
    }

    float lg[8];
    float mx = -1e30f;
#pragma unroll
    for (int e = 0; e < 8; ++e) { lg[e] = acc[e] + bg[e]; mx = fmaxf(mx, lg[e]); }
    float sum = 0.f;
#pragma unroll
    for (int e = 0; e < 8; ++e) { lg[e] = expf(lg[e] - mx); sum += lg[e]; }
    float inv = 1.f / sum;

    float s1 = -1.f, s2 = -1.f; int i1 = 0, i2 = 0;
#pragma unroll
    for (int e = 0; e < 8; ++e) {
        float g = lg[e] * inv;
        if (g > s1)      { s2 = s1; i2 = i1; s1 = g; i1 = e; }
        else if (g > s2) { s2 = g;  i2 = e; }
    }
    if (lane == 0) {
        s12[token * 2]     = s1;
        s12[token * 2 + 1] = s2;
        if (token == 0) { eidx[0] = i1; eidx[1] = i2; }
    }
}

// ------------------------------------------------------------- x -> bf16 --
__global__ void xconv_kernel(const float* __restrict__ x,
                             unsigned short* __restrict__ xb) {
    const int total = N_TOK * D_IN / 8;
    for (int idx = blockIdx.x * blockDim.x + threadIdx.x; idx < total;
         idx += gridDim.x * blockDim.x) {
        const float4* s = (const float4*)(x + (size_t)idx * 8);
        float4 a = s[0], b = s[1];
        u16x8 v;
        v[0] = f2bf(a.x); v[1] = f2bf(a.y); v[2] = f2bf(a.z); v[3] = f2bf(a.w);
        v[4] = f2bf(b.x); v[5] = f2bf(b.y); v[6] = f2bf(b.z); v[7] = f2bf(b.w);
        *(u16x8*)(xb + (size_t)idx * 8) = v;
    }
}

// --------------------------------------- W[e0],W[e1] -> bf16 transposed --
// W_experts[e] is [K=D_IN][N=D_HID] row-major. Output wbT[slot][n][k] (B^T)
// so the GEMM's B fragment is a contiguous 16B ds_read.
__global__ void wconv_kernel(const float* __restrict__ W,
                             const int* __restrict__ eidx,
                             unsigned short* __restrict__ wbT) {
    __shared__ float tile[64][65];   // pad 65: conflict-light both directions
    const int slot = blockIdx.z;
    const int e    = eidx[slot];
    const int k0   = blockIdx.y * 64;   // source row block (K)
    const int n0   = blockIdx.x * 64;   // source col block (N)
    const float* src = W + (size_t)e * D_IN * D_HID;
    const int t = threadIdx.x;

#pragma unroll
    for (int p = 0; p < 4; ++p) {
        int row = p * 16 + (t >> 4);
        int col = (t & 15) * 4;
        const float* s = src + (size_t)(k0 + row) * D_HID + n0 + col;
        tile[row][col]     = s[0];
        tile[row][col + 1] = s[1];
        tile[row][col + 2] = s[2];
        tile[row][col + 3] = s[3];
    }
    __syncthreads();

    unsigned short* dst = wbT + (size_t)slot * D_IN * D_HID;
#pragma unroll
    for (int p = 0; p < 2; ++p) {
        int n = p * 32 + (t >> 3);
        int g = (t & 7) * 8;
        u16x8 v;
#pragma unroll
        for (int j = 0; j < 8; ++j) v[j] = f2bf(tile[g + j][n]);
        *(u16x8*)(dst + (size_t)(n0 + n) * D_IN + k0 + g) = v;
    }
}

// ------------------------------------------------------------------ GEMM --
// 128x128 output tile, BK=64, 4 waves (2x2 of 64x64), dual-expert fused:
// A-tile staged once per K-step, B0/B1 tiles for experts e0/e1, dual
// accumulators, epilogue applies bias + per-row (s1,s2) weighting.
#define GLD16(gp, lp)                                                        \
    __builtin_amdgcn_global_load_lds(                                        \
        (const __attribute__((address_space(1))) void*)(gp),                 \
        (__attribute__((address_space(3))) void*)(lp), 16, 0, 0)

__global__ __launch_bounds__(256) void moe_gemm_kernel(
    const unsigned short* __restrict__ xb,   // [N_TOK][D_IN] bf16
    const unsigned short* __restrict__ wbT,  // [2][D_HID][D_IN] bf16 (B^T)
    const float* __restrict__ b_exp,         // [8][D_HID]
    const int* __restrict__ eidx,
    const float* __restrict__ s12,           // [N_TOK][2]
    float* __restrict__ out) {
    __shared__ __align__(16) short lds[3 * 128 * 64];  // A | B0 | B1, 48 KiB

    const int t    = threadIdx.x;
    const int lane = t & 63;
    const int w    = t >> 6;
    const int mbase = blockIdx.y * 128;
    const int nbase = blockIdx.x * 128;

    // staging addressing: thread t covers tile row (t/8), cols (t%8)*8..+7
    const int arow = t >> 3;
    const int acol = (t & 7) * 8;
    const unsigned short* gA  = xb  + (size_t)(mbase + arow) * D_IN + acol;
    const unsigned short* gB0 = wbT + (size_t)(nbase + arow) * D_IN + acol;
    const unsigned short* gB1 = gB0 + (size_t)D_IN * D_HID;

    f32x4 acc0[4][4], acc1[4][4];
#pragma unroll
    for (int m = 0; m < 4; ++m)
#pragma unroll
        for (int n = 0; n < 4; ++n) {
            acc0[m][n] = (f32x4){0.f, 0.f, 0.f, 0.f};
            acc1[m][n] = (f32x4){0.f, 0.f, 0.f, 0.f};
        }

    // stage K-step 0
#pragma unroll
    for (int j = 0; j < 4; ++j) {
        GLD16(gA  + j * 32 * D_IN, &lds[(j * 256 + w * 64) * 8]);
        GLD16(gB0 + j * 32 * D_IN, &lds[8192 + (j * 256 + w * 64) * 8]);
        GLD16(gB1 + j * 32 * D_IN, &lds[16384 + (j * 256 + w * 64) * 8]);
    }

    const int lrow  = lane & 15;
    const int lk    = (lane >> 4) * 8;
    const int aoff  = ((w >> 1) * 64 + lrow) * 64 + lk;
    const int boff0 = 8192 + ((w & 1) * 64 + lrow) * 64 + lk;
    const int boff1 = boff0 + 8192;

    for (int ks = 0; ks < 32; ++ks) {
        __syncthreads();   // staged tile visible (compiler drains vmcnt)
#pragma unroll
        for (int kk = 0; kk < 64; kk += 32) {
            bf16x8 a[4], b0[4], b1[4];
#pragma unroll
            for (int m = 0; m < 4; ++m)
                a[m] = *(const bf16x8*)&lds[aoff + m * 1024 + kk];
#pragma unroll
            for (int n = 0; n < 4; ++n) {
                b0[n] = *(const bf16x8*)&lds[boff0 + n * 1024 + kk];
                b1[n] = *(const bf16x8*)&lds[boff1 + n * 1024 + kk];
            }
#pragma unroll
            for (int m = 0; m < 4; ++m)
#pragma unroll
                for (int n = 0; n < 4; ++n) {
                    acc0[m][n] = __builtin_amdgcn_mfma_f32_16x16x32_bf16(
                        a[m], b0[n], acc0[m][n], 0, 0, 0);
                    acc1[m][n] = __builtin_amdgcn_mfma_f32_16x16x32_bf16(
                        a[m], b1[n], acc1[m][n], 0, 0, 0);
                }
        }
        if (ks + 1 < 32) {
            __syncthreads();   // all waves done reading LDS
            const int koff = (ks + 1) * 64;
#pragma unroll
            for (int j = 0; j < 4; ++j) {
                GLD16(gA  + j * 32 * D_IN + koff, &lds[(j * 256 + w * 64) * 8]);
                GLD16(gB0 + j * 32 * D_IN + koff, &lds[8192 + (j * 256 + w * 64) * 8]);
                GLD16(gB1 + j * 32 * D_IN + koff, &lds[16384 + (j * 256 + w * 64) * 8]);
            }
        }
    }

    // epilogue: out[r,c] = s1[r]*(acc0 + b0[c]) + s2[r]*(acc1 + b1[c])
    const int e0 = eidx[0], e1 = eidx[1];
    const float* bb0 = b_exp + (size_t)e0 * D_HID;
    const float* bb1 = b_exp + (size_t)e1 * D_HID;
    const int crow0 = mbase + (w >> 1) * 64 + (lane >> 4) * 4;
    const int ccol0 = nbase + (w & 1) * 64 + lrow;
    const float2* s12v = (const float2*)s12;

#pragma unroll
    for (int n = 0; n < 4; ++n) {
        const int c = ccol0 + n * 16;
        const float b0v = bb0[c];
        const float b1v = bb1[c];
#pragma unroll
        for (int m = 0; m < 4; ++m) {
            const int rb = crow0 + m * 16;
#pragma unroll
            for (int j = 0; j < 4; ++j) {
                const int r = rb + j;
                const float2 s = s12v[r];
                out[(size_t)r * D_HID + c] =
                    s.x * (acc0[m][n][j] + b0v) + s.y * (acc1[m][n][j] + b1v);
            }
        }
    }
}

// ---------------------------------------------------------------- launch --
extern "C" void kernel_launch(void* const* d_in, const int* in_sizes, int n_in,
                              void* d_out, int out_size, void* d_ws, size_t ws_size,
                              hipStream_t stream) {
    const float* x         = (const float*)d_in[0];
    const float* W_experts = (const float*)d_in[1];
    const float* b_experts = (const float*)d_in[2];
    const float* W_gate    = (const float*)d_in[3];
    const float* b_gate    = (const float*)d_in[4];
    float* out = (float*)d_out;

    // workspace layout (needs ~84.2 MB):
    char* ws = (char*)d_ws;
    float* s12  = (float*)ws;                                  // 131072 B
    int*   eidx = (int*)(ws + 131072);                         // 8 B (pad)
    unsigned short* xb  = (unsigned short*)(ws + 262144);      // 67108864 B
    unsigned short* wbT = (unsigned short*)(ws + 262144 + 67108864); // 16777216 B

    gate_kernel<<<N_TOK / 4, 256, 0, stream>>>(x, W_gate, b_gate, s12, eidx);
    xconv_kernel<<<4096, 256, 0, stream>>>(x, xb);
    wconv_kernel<<<dim3(32, 32, 2), 256, 0, stream>>>(W_experts, eidx, wbT);
    moe_gemm_kernel<<<dim3(D_HID / 128, N_TOK / 128), 256, 0, stream>>>(
        xb, wbT, b_experts, eidx, s12, out);
}

// Round 2
// 473.530 us; speedup vs baseline: 1.1861x; 1.1861x over previous
//
#include <hip/hip_runtime.h>
#include <hip/hip_bf16.h>
#include <stdint.h>

#define N_TOK 16384
#define D_IN  2048
#define D_HID 2048

typedef __attribute__((ext_vector_type(8))) short  bf16x8;
typedef __attribute__((ext_vector_type(4))) float  f32x4;
typedef __attribute__((ext_vector_type(8))) unsigned short u16x8;

__device__ __forceinline__ unsigned short f2bf(float f) {
    unsigned int u = __float_as_uint(f);
    u = (u + 0x7FFFu + ((u >> 16) & 1u)) >> 16;
    return (unsigned short)u;
}

// ---------------------------------------------------------------- gate ----
__global__ void gate_kernel(const float* __restrict__ x,
                            const float* __restrict__ Wg,
                            const float* __restrict__ bg,
                            float* __restrict__ s12,
                            int* __restrict__ eidx) {
    const int token = blockIdx.x * 4 + (threadIdx.x >> 6);
    const int lane  = threadIdx.x & 63;
    const float* xr = x + (size_t)token * D_IN;

    float acc[8];
#pragma unroll
    for (int e = 0; e < 8; ++e) acc[e] = 0.f;

    for (int i = lane; i < D_IN; i += 64) {
        float xv = xr[i];
        const float4* wr = (const float4*)(Wg + (size_t)i * 8);
        float4 w0 = wr[0], w1 = wr[1];
        acc[0] += xv * w0.x; acc[1] += xv * w0.y;
        acc[2] += xv * w0.z; acc[3] += xv * w0.w;
        acc[4] += xv * w1.x; acc[5] += xv * w1.y;
        acc[6] += xv * w1.z; acc[7] += xv * w1.w;
    }
#pragma unroll
    for (int off = 32; off > 0; off >>= 1) {
#pragma unroll
        for (int e = 0; e < 8; ++e) acc[e] += __shfl_xor(acc[e], off);
    }

    float lg[8];
    float mx = -1e30f;
#pragma unroll
    for (int e = 0; e < 8; ++e) { lg[e] = acc[e] + bg[e]; mx = fmaxf(mx, lg[e]); }
    float sum = 0.f;
#pragma unroll
    for (int e = 0; e < 8; ++e) { lg[e] = expf(lg[e] - mx); sum += lg[e]; }
    float inv = 1.f / sum;

    float s1 = -1.f, s2 = -1.f; int i1 = 0, i2 = 0;
#pragma unroll
    for (int e = 0; e < 8; ++e) {
        float g = lg[e] * inv;
        if (g > s1)      { s2 = s1; i2 = i1; s1 = g; i1 = e; }
        else if (g > s2) { s2 = g;  i2 = e; }
    }
    if (lane == 0) {
        s12[token * 2]     = s1;
        s12[token * 2 + 1] = s2;
        if (token == 0) { eidx[0] = i1; eidx[1] = i2; }
    }
}

// ------------------------------------------------------------- x -> bf16 --
__global__ void xconv_kernel(const float* __restrict__ x,
                             unsigned short* __restrict__ xb) {
    const int total = N_TOK * D_IN / 8;
    for (int idx = blockIdx.x * blockDim.x + threadIdx.x; idx < total;
         idx += gridDim.x * blockDim.x) {
        const float4* s = (const float4*)(x + (size_t)idx * 8);
        float4 a = s[0], b = s[1];
        u16x8 v;
        v[0] = f2bf(a.x); v[1] = f2bf(a.y); v[2] = f2bf(a.z); v[3] = f2bf(a.w);
        v[4] = f2bf(b.x); v[5] = f2bf(b.y); v[6] = f2bf(b.z); v[7] = f2bf(b.w);
        *(u16x8*)(xb + (size_t)idx * 8) = v;
    }
}

// --------------------------------------- W[e0],W[e1] -> bf16 transposed --
__global__ void wconv_kernel(const float* __restrict__ W,
                             const int* __restrict__ eidx,
                             unsigned short* __restrict__ wbT) {
    __shared__ float tile[64][65];
    const int slot = blockIdx.z;
    const int e    = eidx[slot];
    const int k0   = blockIdx.y * 64;
    const int n0   = blockIdx.x * 64;
    const float* src = W + (size_t)e * D_IN * D_HID;
    const int t = threadIdx.x;

#pragma unroll
    for (int p = 0; p < 4; ++p) {
        int row = p * 16 + (t >> 4);
        int col = (t & 15) * 4;
        const float* s = src + (size_t)(k0 + row) * D_HID + n0 + col;
        tile[row][col]     = s[0];
        tile[row][col + 1] = s[1];
        tile[row][col + 2] = s[2];
        tile[row][col + 3] = s[3];
    }
    __syncthreads();

    unsigned short* dst = wbT + (size_t)slot * D_IN * D_HID;
#pragma unroll
    for (int p = 0; p < 2; ++p) {
        int n = p * 32 + (t >> 3);
        int g = (t & 7) * 8;
        u16x8 v;
#pragma unroll
        for (int j = 0; j < 8; ++j) v[j] = f2bf(tile[g + j][n]);
        *(u16x8*)(dst + (size_t)(n0 + n) * D_IN + k0 + g) = v;
    }
}

// ------------------------------------------------------------------ GEMM --
// 256 rows x 128 out-cols x 2 experts, BK=32, 4 LDS buffers (counted vmcnt,
// 3 tiles in flight), 2 phases/K-tile of 16 MFMA each, setprio clusters.
// LDS tiles k-slot-major [4][256]x16B: global_load_lds-linear AND ds_read
// bank-balanced (8 accesses/bank-quad = wave64 b128 floor).
#define GLD16(gp, lp)                                                        \
    __builtin_amdgcn_global_load_lds(                                        \
        (const __attribute__((address_space(1))) void*)(gp),                 \
        (__attribute__((address_space(3))) void*)(lp), 16, 0, 0)

#define LDSV(SLOT) (*(const bf16x8*)&lds[(SLOT) * 8])

#define STAGE_A(SBAS, KOFF)                                                  \
    do {                                                                     \
        GLD16(gA0 + (KOFF),      &lds[((SBAS) + wslot) * 8]);                \
        GLD16(gA0 + (KOFF) + 16, &lds[((SBAS) + 512 + wslot) * 8]);          \
    } while (0)
#define STAGE_B(SBAS, KOFF)                                                  \
    do {                                                                     \
        GLD16(gB0 + (KOFF),      &lds[((SBAS) + 1024 + wslot) * 8]);         \
        GLD16(gB0 + (KOFF) + 16, &lds[((SBAS) + 1536 + wslot) * 8]);         \
    } while (0)

#define MF(MI, AV)                                                                              \
    acc[MI][0] = __builtin_amdgcn_mfma_f32_16x16x32_bf16(AV, bf0, acc[MI][0], 0, 0, 0);         \
    acc[MI][1] = __builtin_amdgcn_mfma_f32_16x16x32_bf16(AV, bf1, acc[MI][1], 0, 0, 0);         \
    acc[MI][2] = __builtin_amdgcn_mfma_f32_16x16x32_bf16(AV, bf2, acc[MI][2], 0, 0, 0);         \
    acc[MI][3] = __builtin_amdgcn_mfma_f32_16x16x32_bf16(AV, bf3, acc[MI][3], 0, 0, 0);

#define TILE(RB, SB, KOFF, DO_STAGE)                                         \
    do {                                                                     \
        const int rbas  = (RB) * 2048;                                       \
        const int abase = rbas + aks + arow;                                 \
        const int bbase = rbas + 1024 + aks + brow;                          \
        bf16x8 bf0 = LDSV(bbase), bf1 = LDSV(bbase + 16),                    \
               bf2 = LDSV(bbase + 32), bf3 = LDSV(bbase + 48);               \
        {                                                                    \
            bf16x8 a0 = LDSV(abase), a1 = LDSV(abase + 16),                  \
                   a2 = LDSV(abase + 32), a3 = LDSV(abase + 48);             \
            if (DO_STAGE) STAGE_A((SB) * 2048, KOFF);                        \
            __builtin_amdgcn_s_setprio(1);                                   \
            MF(0, a0) MF(1, a1) MF(2, a2) MF(3, a3)                          \
            __builtin_amdgcn_s_setprio(0);                                   \
        }                                                                    \
        __builtin_amdgcn_s_barrier();                                        \
        {                                                                    \
            bf16x8 a4 = LDSV(abase + 64), a5 = LDSV(abase + 80),             \
                   a6 = LDSV(abase + 96), a7 = LDSV(abase + 112);            \
            if (DO_STAGE) STAGE_B((SB) * 2048, KOFF);                        \
            __builtin_amdgcn_s_setprio(1);                                   \
            MF(4, a4) MF(5, a5) MF(6, a6) MF(7, a7)                          \
            __builtin_amdgcn_s_setprio(0);                                   \
        }                                                                    \
    } while (0)

__global__ __launch_bounds__(512, 2) void moe_gemm_kernel(
    const unsigned short* __restrict__ xb,   // [N_TOK][D_IN] bf16
    const unsigned short* __restrict__ wbT,  // [2][D_HID][D_IN] bf16 (B^T)
    const float* __restrict__ b_exp,         // [8][D_HID]
    const int* __restrict__ eidx,
    const float* __restrict__ s12,           // [N_TOK][2]
    float* __restrict__ out) {
    // 4 buffers x (A:1024 + B:1024 slots) x 16B = 128 KiB
    __shared__ __align__(16) short lds[4 * 2048 * 8];

    const int t512 = threadIdx.x;
    const int lane = t512 & 63;
    const int w    = t512 >> 6;
    const int wm   = w >> 2;      // 0..1 : row half
    const int wn   = w & 3;       // 0..1 expert0 cols, 2..3 expert1 cols
    const int wslot = w * 64;

    // XCD-aware bijective swizzle (1024 % 8 == 0)
    const int bid = blockIdx.x;
    const int wg  = (bid & 7) * 128 + (bid >> 3);
    const int by  = wg >> 4;                  // 64 M-tiles
    const int bx  = wg & 15;                  // 16 col-tiles
    const int mbase = by * 256;
    const int nbase = bx * 128;

    // staging source pointers (thread t covers slots t and 512+t per matrix)
    const int arow_g = t512 & 255;            // global row within tile
    const int aks_g  = t512 >> 8;             // k-slot 0..1 (j=1 adds +2)
    const unsigned short* gA0 =
        xb + (size_t)(mbase + arow_g) * D_IN + aks_g * 8;
    const int be  = arow_g >> 7;              // expert select
    const int bcl = nbase + (arow_g & 127);   // expert-local column
    const unsigned short* gB0 =
        wbT + ((size_t)be * D_HID + bcl) * D_IN + aks_g * 8;

    // ds_read bases (slot units)
    const int aks  = (lane >> 4) * 256;       // k-slot of this lane
    const int arow = wm * 128 + (lane & 15);  // + mi*16
    const int brow = wn * 64 + (lane & 15);   // + ni*16

    f32x4 acc[8][4];
#pragma unroll
    for (int mi = 0; mi < 8; ++mi)
#pragma unroll
        for (int ni = 0; ni < 4; ++ni) acc[mi][ni] = (f32x4){0.f, 0.f, 0.f, 0.f};

    // prologue: stage tiles 0,1,2
    STAGE_A(0, 0);    STAGE_B(0, 0);
    STAGE_A(2048, 32); STAGE_B(2048, 32);
    STAGE_A(4096, 64); STAGE_B(4096, 64);
    asm volatile("s_waitcnt vmcnt(8)" ::: "memory");
    __builtin_amdgcn_s_barrier();

#pragma unroll 4
    for (int t = 0; t < 61; ++t) {
        TILE(t & 3, (t + 3) & 3, (t + 3) * 32, 1);
        asm volatile("s_waitcnt vmcnt(8)" ::: "memory");
        __builtin_amdgcn_s_barrier();
    }
    TILE(1, 0, 0, 0);
    asm volatile("s_waitcnt vmcnt(4)" ::: "memory");
    __builtin_amdgcn_s_barrier();
    TILE(2, 0, 0, 0);
    asm volatile("s_waitcnt vmcnt(0)" ::: "memory");
    __builtin_amdgcn_s_barrier();
    TILE(3, 0, 0, 0);

    // -------- epilogue: combine experts through LDS (f32) --------
    __syncthreads();
    float* fl = (float*)lds;
    if (wn >= 2) {
        float* reg = fl + (wm * 2 + (wn - 2)) * 8192;   // [128][64]
#pragma unroll
        for (int mi = 0; mi < 8; ++mi)
#pragma unroll
            for (int ni = 0; ni < 4; ++ni)
#pragma unroll
                for (int j = 0; j < 4; ++j) {
                    int row_l = mi * 16 + ((lane >> 4) << 2) + j;
                    int col_l = ni * 16 + (lane & 15);
                    reg[row_l * 64 + col_l] = acc[mi][ni][j];
                }
    }
    __syncthreads();
    if (wn < 2) {
        const float* reg = fl + (wm * 2 + wn) * 8192;
        const int e0 = eidx[0], e1 = eidx[1];
        const float* bb0 = b_exp + (size_t)e0 * D_HID;
        const float* bb1 = b_exp + (size_t)e1 * D_HID;
        const float2* s12v = (const float2*)s12;
        int   cc[4];
        float b0c[4], b1c[4];
#pragma unroll
        for (int ni = 0; ni < 4; ++ni) {
            cc[ni]  = nbase + wn * 64 + ni * 16 + (lane & 15);
            b0c[ni] = bb0[cc[ni]];
            b1c[ni] = bb1[cc[ni]];
        }
#pragma unroll
        for (int mi = 0; mi < 8; ++mi)
#pragma unroll
            for (int j = 0; j < 4; ++j) {
                int row_l = mi * 16 + ((lane >> 4) << 2) + j;
                int r = mbase + wm * 128 + row_l;
                float2 s = s12v[r];
#pragma unroll
                for (int ni = 0; ni < 4; ++ni) {
                    float y1 = reg[row_l * 64 + ni * 16 + (lane & 15)];
                    out[(size_t)r * D_HID + cc[ni]] =
                        s.x * (acc[mi][ni][j] + b0c[ni]) + s.y * (y1 + b1c[ni]);
                }
            }
    }
}

// ---------------------------------------------------------------- launch --
extern "C" void kernel_launch(void* const* d_in, const int* in_sizes, int n_in,
                              void* d_out, int out_size, void* d_ws, size_t ws_size,
                              hipStream_t stream) {
    const float* x         = (const float*)d_in[0];
    const float* W_experts = (const float*)d_in[1];
    const float* b_experts = (const float*)d_in[2];
    const float* W_gate    = (const float*)d_in[3];
    const float* b_gate    = (const float*)d_in[4];
    float* out = (float*)d_out;

    char* ws = (char*)d_ws;
    float* s12  = (float*)ws;                                        // 128 KiB
    int*   eidx = (int*)(ws + 131072);
    unsigned short* xb  = (unsigned short*)(ws + 262144);            // 64 MiB
    unsigned short* wbT = (unsigned short*)(ws + 262144 + 67108864); // 16 MiB

    gate_kernel<<<N_TOK / 4, 256, 0, stream>>>(x, W_gate, b_gate, s12, eidx);
    xconv_kernel<<<4096, 256, 0, stream>>>(x, xb);
    wconv_kernel<<<dim3(32, 32, 2), 256, 0, stream>>>(W_experts, eidx, wbT);
    moe_gemm_kernel<<<1024, 512, 0, stream>>>(xb, wbT, b_experts, eidx, s12, out);
}